// Round 6
// baseline (346.289 us; speedup 1.0000x reference)
//
#include <hip/hip_runtime.h>
#include <stdint.h>

// Net_49177375539428: recursive tree-NN scorer, all-fp32.
//   k_base : base[n,:] = vecs[data[n]] @ Wd + bd ; d_score at n==pos.
//            (round-2 version, verbatim)
//   k_tree : dataflow (round-5 structure, validated) + ASM-PIPELINED GEMV:
//            round-5 showed VGPR=60 -> ~1-2 W-loads in flight/wave ->
//            74 GB/s/CU (half the ~153 GB/s port floor). The compiler's
//            reg-pressure heuristic serializes HIP-level prefetch, so the
//            inner loop is now inline asm: global_load_dwordx4 groups of 4
//            rows, rolling s_waitcnt vmcnt(4) (never 0 until the end),
//            sched_barrier(0) fences per rule #18. Consume order is
//            strictly d-ascending per half -> bit-identical math.
//   k_step0: one block per edge-type e: W[e] streamed once, reused across
//            all 8 graphs (round-2 version, verbatim).
//   k_steps: path chain, 16 e-rows per block (round-2 version, verbatim).

#define NND 128
#define DD  128
#define GG  8
#define VD  300
#define EDGEN 128
#define CH2 16         // e-rows per k_steps block

typedef unsigned int u32;

#define F_POS  (1<<16)
#define F_PATH (1<<17)

// ---------------- K1: base embeddings + d_score ----------------
__global__ void __launch_bounds__(128) k_base(
        const int* __restrict__ data, const int* __restrict__ posArr,
        const float* __restrict__ vecs, const float* __restrict__ dw,
        const float* __restrict__ db,   const float* __restrict__ sdw,
        const float* __restrict__ sb,
        float* __restrict__ base, float* __restrict__ dscore)
{
    __shared__ __align__(16) float row[VD];
    __shared__ float red[DD];
    int n = blockIdx.x, t = threadIdx.x;
    int id = data[n];
    const float4* vp = (const float4*)(vecs + (size_t)id * VD);  // 1200B rows
    for (int i = t; i < VD/4; i += 128) ((float4*)row)[i] = vp[i];
    __syncthreads();
    float a0 = db[t], a1 = 0.f, a2 = 0.f, a3 = 0.f;
    for (int d = 0; d < VD; d += 4){
        a0 = fmaf(row[d+0], dw[(d+0)*DD + t], a0);
        a1 = fmaf(row[d+1], dw[(d+1)*DD + t], a1);
        a2 = fmaf(row[d+2], dw[(d+2)*DD + t], a2);
        a3 = fmaf(row[d+3], dw[(d+3)*DD + t], a3);
    }
    float acc = (a0 + a1) + (a2 + a3);
    base[n*DD + t] = acc;
    if (n == posArr[0]){
        red[t] = acc * sdw[t];
        __syncthreads();
        for (int o = 64; o > 0; o >>= 1){ if (t < o) red[t] += red[t+o]; __syncthreads(); }
        if (t == 0) dscore[0] = sb[0] + red[0];
    }
}

// ---------------- K2: dataflow tree sweep, asm-pipelined GEMV ----------------
__global__ void __launch_bounds__(1024, 1) k_tree(
        const int* __restrict__ graphs, const int* __restrict__ edges,
        const int* __restrict__ posArr, const float* __restrict__ EW,
        const float* __restrict__ EB,   const float* __restrict__ base,
        float* __restrict__ vposG, float* __restrict__ uG, int* __restrict__ meta)
{
    __shared__ __align__(16) float contrib[NND-1][DD];   // 63.5 KB, nodes 0..126
    __shared__ int par_s[NND], eid_s[NND], flg_s[NND];
    __shared__ int ccnt[NND], cstart[NND], cidx[NND];
    __shared__ int kcnt[NND];          // remaining-children counters
    __shared__ int queue[NND];         // monotonic ready-queue (node ids)
    __shared__ int qhead, qtail;

    int g = blockIdx.x, t = threadIdx.x;

    // ---- phase 1: load graph structure, init queue ----
    if (t < NND){
        par_s[t] = (t < NND-1) ? (t + graphs[g*NND + t]) : (NND-1);  // root self-parent
        eid_s[t] = edges[t];
        flg_s[t] = 0;
        ccnt[t]  = 0;
        queue[t] = -1;
    }
    if (t == 0){ qhead = 0; qtail = 0; }
    __syncthreads();

    // ---- phase 2: child counts, sibling slots, path walk ----
    int mySlot = 0;
    if (t < NND-1){
        int p = par_s[t];
        atomicAdd(&ccnt[p], 1);
        for (int c = 0; c < t; ++c) mySlot += (par_s[c] == p);  // ascending order
    }
    if (t == 0){
        int p = posArr[0];
        flg_s[p] |= F_POS;
        int c = par_s[p], s = 0;
        for (;;){
            flg_s[c] |= F_PATH | (s << 24);
            meta[g*(NND+1) + 1 + s] = c;
            ++s;
            if (c == NND-1) break;
            c = par_s[c];
        }
        meta[g*(NND+1)] = s;                        // path length L
    }
    __syncthreads();

    // ---- phase 3: child list offsets, counters, leaf pushes ----
    if (t < NND){
        int s = 0;
        for (int p = 0; p < t; ++p) s += ccnt[p];
        cstart[t] = s;
        kcnt[t] = ccnt[t];
    }
    __syncthreads();
    if (t < NND-1) cidx[cstart[par_s[t]] + mySlot] = t;
    if (t < NND && ccnt[t] == 0){
        int slot = atomicAdd(&qtail, 1);
        queue[slot] = t;                            // leaves ready immediately
    }
    __syncthreads();

    // ---- main: dataflow loop, no barriers ----
    int l = t & 63;
    int c0 = 2*l;                       // gather mapping: 2 cols/lane
    int li = l & 31, hl = l >> 5;       // GEMV mapping: 4 cols x half-d
    int c4 = 4*li, dbase = 64*hl;

    // gather + classify; stage emb in contrib[n] if plain-GEMV node
    auto prep = [&](int n)->bool{
        float2 bse = *(const float2*)&base[n*DD + c0];
        float e0 = bse.x, e1 = bse.y;
        int cs = cstart[n], cc = ccnt[n];
        for (int j = 0; j < cc; ++j){
            int c = cidx[cs + j];
            if (!(flg_s[c] & (F_POS | F_PATH))){
                float2 cv = *(const float2*)&contrib[c][c0];
                e0 += cv.x; e1 += cv.y;
            }
        }
        int f = flg_s[n];
        if (f & F_POS){
            if (cc){ e0 = fmaxf(e0, 0.f); e1 = fmaxf(e1, 0.f); }
            *(float2*)&vposG[g*DD + c0] = make_float2(e0, e1);
            return false;
        }
        if (f & F_PATH){
            int slot = ((u32)f) >> 24;
            *(float2*)&uG[((size_t)g*NND + slot)*DD + c0] = make_float2(e0, e1);  // pre-relu
            return false;
        }
        if (cc){ e0 = fmaxf(e0, 0.f); e1 = fmaxf(e1, 0.f); }
        *(float2*)&contrib[n][c0] = make_float2(e0, e1);       // stage emb
        return true;
    };

    // asm-pipelined GEMV: rolling vmcnt(4), 2x4 float4 reg groups.
    // Group k = rows 4k..4k+3 of this lane's half (byte stride 512/row,
    // group base Wp + k*512 floats). Consume order strictly d-ascending.
    auto gemv1 = [&](int n){
        int e = eid_s[n];
        const float* Wp = EW + (size_t)e*(DD*DD) + (size_t)dbase*DD + c4;
        const float* xr = &contrib[n][dbase];
        float s0=0.f, s1=0.f, s2=0.f, s3=0.f;
        float4 A0,A1,A2,A3, B0,B1,B2,B3;
#define GISSUE(r0,r1,r2,r3, pp) \
        asm volatile("global_load_dwordx4 %0, %4, off\n\t" \
                     "global_load_dwordx4 %1, %4, off offset:512\n\t" \
                     "global_load_dwordx4 %2, %4, off offset:1024\n\t" \
                     "global_load_dwordx4 %3, %4, off offset:1536" \
                     : "=&v"(r0),"=&v"(r1),"=&v"(r2),"=&v"(r3) : "v"(pp))
#define GWAIT4 do { asm volatile("s_waitcnt vmcnt(4)" ::: "memory"); \
                    __builtin_amdgcn_sched_barrier(0); } while(0)
#define GWAIT0 do { asm volatile("s_waitcnt vmcnt(0)" ::: "memory"); \
                    __builtin_amdgcn_sched_barrier(0); } while(0)
#define GCONS(r0,r1,r2,r3, gi) do { \
        float4 xv = *(const float4*)&xr[(gi)*4]; \
        s0=fmaf(xv.x,r0.x,s0); s1=fmaf(xv.x,r0.y,s1); s2=fmaf(xv.x,r0.z,s2); s3=fmaf(xv.x,r0.w,s3); \
        s0=fmaf(xv.y,r1.x,s0); s1=fmaf(xv.y,r1.y,s1); s2=fmaf(xv.y,r1.z,s2); s3=fmaf(xv.y,r1.w,s3); \
        s0=fmaf(xv.z,r2.x,s0); s1=fmaf(xv.z,r2.y,s1); s2=fmaf(xv.z,r2.z,s2); s3=fmaf(xv.z,r2.w,s3); \
        s0=fmaf(xv.w,r3.x,s0); s1=fmaf(xv.w,r3.y,s1); s2=fmaf(xv.w,r3.z,s2); s3=fmaf(xv.w,r3.w,s3); \
        } while(0)
        GISSUE(A0,A1,A2,A3, Wp);
        GISSUE(B0,B1,B2,B3, Wp+512);
        GWAIT4; GCONS(A0,A1,A2,A3, 0);  GISSUE(A0,A1,A2,A3, Wp+1024);
        GWAIT4; GCONS(B0,B1,B2,B3, 1);  GISSUE(B0,B1,B2,B3, Wp+1536);
        GWAIT4; GCONS(A0,A1,A2,A3, 2);  GISSUE(A0,A1,A2,A3, Wp+2048);
        GWAIT4; GCONS(B0,B1,B2,B3, 3);  GISSUE(B0,B1,B2,B3, Wp+2560);
        GWAIT4; GCONS(A0,A1,A2,A3, 4);  GISSUE(A0,A1,A2,A3, Wp+3072);
        GWAIT4; GCONS(B0,B1,B2,B3, 5);  GISSUE(B0,B1,B2,B3, Wp+3584);
        GWAIT4; GCONS(A0,A1,A2,A3, 6);  GISSUE(A0,A1,A2,A3, Wp+4096);
        GWAIT4; GCONS(B0,B1,B2,B3, 7);  GISSUE(B0,B1,B2,B3, Wp+4608);
        GWAIT4; GCONS(A0,A1,A2,A3, 8);  GISSUE(A0,A1,A2,A3, Wp+5120);
        GWAIT4; GCONS(B0,B1,B2,B3, 9);  GISSUE(B0,B1,B2,B3, Wp+5632);
        GWAIT4; GCONS(A0,A1,A2,A3,10);  GISSUE(A0,A1,A2,A3, Wp+6144);
        GWAIT4; GCONS(B0,B1,B2,B3,11);  GISSUE(B0,B1,B2,B3, Wp+6656);
        GWAIT4; GCONS(A0,A1,A2,A3,12);  GISSUE(A0,A1,A2,A3, Wp+7168);
        GWAIT4; GCONS(B0,B1,B2,B3,13);  GISSUE(B0,B1,B2,B3, Wp+7680);
        GWAIT4; GCONS(A0,A1,A2,A3,14);
        GWAIT0; GCONS(B0,B1,B2,B3,15);
#undef GISSUE
#undef GWAIT4
#undef GWAIT0
#undef GCONS
        s0 += __shfl_xor(s0, 32); s1 += __shfl_xor(s1, 32);
        s2 += __shfl_xor(s2, 32); s3 += __shfl_xor(s3, 32);
        if (hl == 0){
            float4 bb = *(const float4*)&EB[(size_t)e*DD + c4];
            *(float4*)&contrib[n][c4] =
                make_float4(s0 + bb.x, s1 + bb.y, s2 + bb.z, s3 + bb.w);
        }
    };

    for (;;){
        int idx = 0;
        if (l == 0) idx = atomicAdd(&qhead, 1);     // claim a queue slot
        idx = __shfl(idx, 0);
        if (idx >= NND) break;                       // all nodes claimed
        volatile int* qp = (volatile int*)&queue[idx];
        int n;
        while ((n = *qp) < 0) ;                      // spin till slot filled
        bool doG = prep(n);
        asm volatile("s_waitcnt lgkmcnt(0)" ::: "memory");   // staged emb RAW
        if (doG) gemv1(n);
        asm volatile("s_waitcnt lgkmcnt(0)" ::: "memory");   // y write complete
        if (l == 0 && n != NND-1){
            int p = par_s[n];
            int old = atomicSub(&kcnt[p], 1);
            if (old == 1){                           // last child -> parent ready
                int slot = atomicAdd(&qtail, 1);
                queue[slot] = p;
            }
        }
    }
}

// ---------------- K3a: step 0, batched over graphs ----------------
__global__ void __launch_bounds__(256, 1) k_step0(
        const float* __restrict__ EW, const float* __restrict__ EB,
        const float* __restrict__ vposG, const float* __restrict__ uG,
        float* __restrict__ V0)
{
    __shared__ __align__(16) float vpos_s[GG][DD];
    int e = blockIdx.x, t = threadIdx.x, l = t & 63, w = t >> 6;
    {
        int idx = t;                                 // GG*DD/4 == 256 exactly
        ((float4*)vpos_s)[idx] = ((const float4*)vposG)[idx];
    }
    __syncthreads();
    int k4 = w*8 + (l & 7);
    int d0 = (l >> 3) * 16;
    bool owner = ((l >> 3) == 0);
    const float* Wp = EW + (size_t)e*(DD*DD) + (size_t)d0*DD + 4*k4;
    float4 wr[16];
    #pragma unroll
    for (int d = 0; d < 16; ++d) wr[d] = *(const float4*)&Wp[d*DD];
    float4 bb = *(const float4*)&EB[(size_t)e*DD + 4*k4];
    for (int g = 0; g < GG; ++g){
        float s0=0.f, s1=0.f, s2=0.f, s3=0.f;
        #pragma unroll
        for (int d = 0; d < 16; ++d){
            float x = vpos_s[g][d0 + d];
            s0 = fmaf(x, wr[d].x, s0);
            s1 = fmaf(x, wr[d].y, s1);
            s2 = fmaf(x, wr[d].z, s2);
            s3 = fmaf(x, wr[d].w, s3);
        }
        #pragma unroll
        for (int m = 8; m <= 32; m <<= 1){
            s0 += __shfl_xor(s0, m); s1 += __shfl_xor(s1, m);
            s2 += __shfl_xor(s2, m); s3 += __shfl_xor(s3, m);
        }
        if (owner){
            float4 u0 = *(const float4*)&uG[(size_t)g*NND*DD + 4*k4];
            float4 r;
            r.x = fmaxf(u0.x + s0 + bb.x, 0.f);
            r.y = fmaxf(u0.y + s1 + bb.y, 0.f);
            r.z = fmaxf(u0.z + s2 + bb.z, 0.f);
            r.w = fmaxf(u0.w + s3 + bb.w, 0.f);
            *(float4*)&V0[((size_t)g*EDGEN + e)*DD + 4*k4] = r;
        }
    }
}

// ---------------- K3b: path chains, 16 e-rows per block ----------------
__global__ void __launch_bounds__(256, 1) k_steps(
        const int* __restrict__ edges,
        const float* __restrict__ EW, const float* __restrict__ EB,
        const float* __restrict__ SEW,
        const float* __restrict__ uG, const float* __restrict__ V0,
        const int* __restrict__ meta, const float* __restrict__ dscore,
        float* __restrict__ outp)
{
    __shared__ __align__(16) float Vbuf[2][CH2][DD];
    __shared__ float red[CH2][4];
    int g = blockIdx.x >> 3, chunk = blockIdx.x & 7;
    int t = threadIdx.x, l = t & 63, w = t >> 6;
    int k4 = w*8 + (l & 7);
    int d0 = (l >> 3) * 16;
    bool owner = ((l >> 3) == 0);
    int eBase = chunk * CH2;
    int L = meta[g*(NND+1)];

    // load this block's 16 step-0 rows
    for (int idx = t; idx < CH2*DD/4; idx += 256)
        ((float4*)&Vbuf[0][0][0])[idx] =
            ((const float4*)&V0[((size_t)g*EDGEN + eBase)*DD])[idx];
    __syncthreads();

    // ---- shared steps 1..L-1: one W per step, reused across CH2 e-rows ----
    int cur = 0;
    for (int s = 1; s < L; ++s){
        int pn = meta[g*(NND+1) + s];           // path[s-1]
        int ej = edges[pn];
        const float* Wp = EW + (size_t)ej*(DD*DD) + (size_t)d0*DD + 4*k4;
        float4 wr[16];
        #pragma unroll
        for (int d = 0; d < 16; ++d) wr[d] = *(const float4*)&Wp[d*DD];
        float4 us = *(const float4*)&uG[((size_t)g*NND + s)*DD + 4*k4];
        float4 bb = *(const float4*)&EB[(size_t)ej*DD + 4*k4];
        #pragma unroll 4
        for (int p = 0; p < CH2; ++p){
            float ev[16];
            #pragma unroll
            for (int j = 0; j < 4; ++j){
                float4 x = *(const float4*)&Vbuf[cur][p][d0 + 4*j];
                ev[4*j+0]=x.x; ev[4*j+1]=x.y; ev[4*j+2]=x.z; ev[4*j+3]=x.w;
            }
            float s0=0.f, s1=0.f, s2=0.f, s3=0.f;
            #pragma unroll
            for (int d = 0; d < 16; ++d){
                s0 = fmaf(ev[d], wr[d].x, s0);
                s1 = fmaf(ev[d], wr[d].y, s1);
                s2 = fmaf(ev[d], wr[d].z, s2);
                s3 = fmaf(ev[d], wr[d].w, s3);
            }
            #pragma unroll
            for (int m = 8; m <= 32; m <<= 1){
                s0 += __shfl_xor(s0, m); s1 += __shfl_xor(s1, m);
                s2 += __shfl_xor(s2, m); s3 += __shfl_xor(s3, m);
            }
            if (owner){
                float4 r;
                r.x = fmaxf(us.x + s0 + bb.x, 0.f);
                r.y = fmaxf(us.y + s1 + bb.y, 0.f);
                r.z = fmaxf(us.z + s2 + bb.z, 0.f);
                r.w = fmaxf(us.w + s3 + bb.w, 0.f);
                *(float4*)&Vbuf[cur^1][p][4*k4] = r;
            }
        }
        __syncthreads();
        cur ^= 1;
    }

    // ---- final transform (root edge) + score ----
    {
        int rn = meta[g*(NND+1) + L];           // path[L-1] (= 127)
        int er = edges[rn];
        const float* Wp = EW + (size_t)er*(DD*DD) + (size_t)d0*DD + 4*k4;
        float4 wr[16];
        #pragma unroll
        for (int d = 0; d < 16; ++d) wr[d] = *(const float4*)&Wp[d*DD];
        float4 bb = *(const float4*)&EB[(size_t)er*DD + 4*k4];
        float4 sw = *(const float4*)&SEW[4*k4];
        #pragma unroll 4
        for (int p = 0; p < CH2; ++p){
            float ev[16];
            #pragma unroll
            for (int j = 0; j < 4; ++j){
                float4 x = *(const float4*)&Vbuf[cur][p][d0 + 4*j];
                ev[4*j+0]=x.x; ev[4*j+1]=x.y; ev[4*j+2]=x.z; ev[4*j+3]=x.w;
            }
            float s0=0.f, s1=0.f, s2=0.f, s3=0.f;
            #pragma unroll
            for (int d = 0; d < 16; ++d){
                s0 = fmaf(ev[d], wr[d].x, s0);
                s1 = fmaf(ev[d], wr[d].y, s1);
                s2 = fmaf(ev[d], wr[d].z, s2);
                s3 = fmaf(ev[d], wr[d].w, s3);
            }
            #pragma unroll
            for (int m = 8; m <= 32; m <<= 1){
                s0 += __shfl_xor(s0, m); s1 += __shfl_xor(s1, m);
                s2 += __shfl_xor(s2, m); s3 += __shfl_xor(s3, m);
            }
            if (owner){
                float part = (s0 + bb.x) * sw.x + (s1 + bb.y) * sw.y
                           + (s2 + bb.z) * sw.z + (s3 + bb.w) * sw.w;
                part += __shfl_xor(part, 1);
                part += __shfl_xor(part, 2);
                part += __shfl_xor(part, 4);
                if (l == 0) red[p][w] = part;
            }
        }
        __syncthreads();
        if (t < CH2)
            outp[g*DD + eBase + t] = dscore[0] + red[t][0] + red[t][1] + red[t][2] + red[t][3];
    }
}

extern "C" void kernel_launch(void* const* d_in, const int* in_sizes, int n_in,
                              void* d_out, int out_size, void* d_ws, size_t ws_size,
                              hipStream_t stream)
{
    const int*   data   = (const int*)d_in[0];
    /* d_in[1] = types, unused (single data_type) */
    const int*   graphs = (const int*)d_in[2];
    const int*   edges  = (const int*)d_in[3];
    const int*   posArr = (const int*)d_in[4];
    const float* vecs   = (const float*)d_in[5];
    const float* dw     = (const float*)d_in[6];
    const float* db     = (const float*)d_in[7];
    const float* ew     = (const float*)d_in[8];
    const float* eb     = (const float*)d_in[9];
    const float* sew    = (const float*)d_in[10];
    const float* sdw    = (const float*)d_in[11];
    const float* sb     = (const float*)d_in[12];

    char* ws = (char*)d_ws;
    float* base   = (float*)(ws);                               // 64 KB
    float* vposG  = (float*)(ws + 65536);                       // 4 KB
    float* uG     = (float*)(ws + 69632);                       // 512 KB
    float* dscore = (float*)(ws + 593920);                      // 1 f32
    int*   meta   = (int*)  (ws + 594176);                      // 8*129 ints
    float* V0     = (float*)(ws + 598528);                      // 512 KB

    float* outp = (float*)d_out;

    k_base <<<NND, 128, 0, stream>>>(data, posArr, vecs, dw, db, sdw, sb, base, dscore);
    k_tree <<<GG, 1024, 0, stream>>>(graphs, edges, posArr, ew, eb, base, vposG, uG, meta);
    k_step0<<<EDGEN, 256, 0, stream>>>(ew, eb, vposG, uG, V0);
    k_steps<<<GG*(EDGEN/CH2), 256, 0, stream>>>(edges, ew, eb, sew, uG, V0,
                                                meta, dscore, outp);
}

// Round 7
// 318.548 us; speedup vs baseline: 1.0871x; 1.0871x over previous
//
#include <hip/hip_runtime.h>
#include <stdint.h>

// Net_49177375539428: recursive tree-NN scorer, all-fp32.
//   k_base : base GEMV + d_score (round-2 verbatim) + zeroing of the
//            per-(graph,level) barrier flags used by k_treeX.
//   k_treeX: MULTI-CU level-synchronous tree sweep. 64 blocks (8 per graph)
//            x 1024 thr. Children are at exactly depth(parent)+1, so levels
//            have zero intra-level deps -> within a level, node q belongs to
//            block (q mod 8); each block runs the EXACT validated full-width
//            gemv (bit-identical association); contribs live in global
//            contribX (overlaid on V0, dead before k_step0); levels are
//            separated by an 8-block flag barrier (threadfence + device-
//            scope atomics; LLC is the coherence point). Spreads the
//            7.8MB/graph W-stream over 8 CUs: ~106us (1 CU at its measured
//            74 GB/s ceiling) -> ~13us stream + ~15 level barriers.
//   k_step0: one block per edge-type e (round-2 verbatim).
//   k_steps: path chain, 16 e-rows per block (round-2 verbatim).

#define NND 128
#define DD  128
#define GG  8
#define VD  300
#define EDGEN 128
#define CH2 16         // e-rows per k_steps block
#define KSP 8          // blocks per graph in k_treeX

typedef unsigned int u32;

#define F_POS  (1<<16)
#define F_PATH (1<<17)
#define SKIPF  (F_POS|F_PATH)

// ---------------- K1: base embeddings + d_score + flag zero ----------------
__global__ void __launch_bounds__(128) k_base(
        const int* __restrict__ data, const int* __restrict__ posArr,
        const float* __restrict__ vecs, const float* __restrict__ dw,
        const float* __restrict__ db,   const float* __restrict__ sdw,
        const float* __restrict__ sb,
        float* __restrict__ base, float* __restrict__ dscore,
        int* __restrict__ flagsG)
{
    __shared__ __align__(16) float row[VD];
    __shared__ float red[DD];
    int n = blockIdx.x, t = threadIdx.x;
    if (n < GG) flagsG[n*NND + t] = 0;          // level-barrier flags for k_treeX
    int id = data[n];
    const float4* vp = (const float4*)(vecs + (size_t)id * VD);  // 1200B rows
    for (int i = t; i < VD/4; i += 128) ((float4*)row)[i] = vp[i];
    __syncthreads();
    float a0 = db[t], a1 = 0.f, a2 = 0.f, a3 = 0.f;
    for (int d = 0; d < VD; d += 4){
        a0 = fmaf(row[d+0], dw[(d+0)*DD + t], a0);
        a1 = fmaf(row[d+1], dw[(d+1)*DD + t], a1);
        a2 = fmaf(row[d+2], dw[(d+2)*DD + t], a2);
        a3 = fmaf(row[d+3], dw[(d+3)*DD + t], a3);
    }
    float acc = (a0 + a1) + (a2 + a3);
    base[n*DD + t] = acc;
    if (n == posArr[0]){
        red[t] = acc * sdw[t];
        __syncthreads();
        for (int o = 64; o > 0; o >>= 1){ if (t < o) red[t] += red[t+o]; __syncthreads(); }
        if (t == 0) dscore[0] = sb[0] + red[0];
    }
}

// ---------------- K2: multi-CU level-synchronous tree sweep ----------------
__global__ void __launch_bounds__(1024, 1) k_treeX(
        const int* __restrict__ graphs, const int* __restrict__ edges,
        const int* __restrict__ posArr, const float* __restrict__ EW,
        const float* __restrict__ EB,   const float* __restrict__ base,
        float* __restrict__ vposG, float* __restrict__ uG, int* __restrict__ meta,
        float* __restrict__ contribX, int* __restrict__ flagsG)
{
    __shared__ __align__(16) float xstage[16][DD];       // per-wave emb stage, 8KB
    __shared__ int par_s[NND], eid_s[NND], flg_s[NND];
    __shared__ int ccnt[NND], cstart[NND], cidx[NND];
    __shared__ int dep[NND], anc[NND], lcnt[NND], lstart[NND], order[NND];
    __shared__ int maxD_s;

    int b = blockIdx.x, g = b >> 3, k = b & (KSP-1), t = threadIdx.x;

    // ---- phase 1: load graph structure (identical in all 8 blocks of g) ----
    if (t < NND){
        par_s[t] = (t < NND-1) ? (t + graphs[g*NND + t]) : (NND-1);  // root self-parent
        eid_s[t] = edges[t];
        flg_s[t] = 0;
        ccnt[t]  = 0;
        lcnt[t]  = 0;
    }
    if (t == 0) maxD_s = 0;
    __syncthreads();

    // ---- phase 2: child counts, sibling slots, path walk ----
    int mySlot = 0;
    if (t < NND-1){
        int p = par_s[t];
        atomicAdd(&ccnt[p], 1);
        for (int c = 0; c < t; ++c) mySlot += (par_s[c] == p);  // ascending order
    }
    if (t < NND){
        dep[t] = (t < NND-1) ? 1 : 0;
        anc[t] = par_s[t];
    }
    if (t == 0){
        int p = posArr[0];
        flg_s[p] |= F_POS;
        int c = par_s[p], s = 0;
        for (;;){
            flg_s[c] |= F_PATH | (s << 24);
            if (k == 0) meta[g*(NND+1) + 1 + s] = c;
            ++s;
            if (c == NND-1) break;
            c = par_s[c];
        }
        if (k == 0) meta[g*(NND+1)] = s;            // path length L
    }
    __syncthreads();

    // ---- phase 3: child list offsets ----
    if (t < NND){
        int s = 0;
        for (int p = 0; p < t; ++p) s += ccnt[p];
        cstart[t] = s;
    }
    __syncthreads();
    if (t < NND-1) cidx[cstart[par_s[t]] + mySlot] = t;

    // ---- phase 4: depth via pointer jumping ----
    for (int kk = 0; kk < 7; ++kk){
        int d2 = 0, a2 = 0;
        if (t < NND){ d2 = dep[t] + dep[anc[t]]; a2 = anc[anc[t]]; }
        __syncthreads();
        if (t < NND){ dep[t] = d2; anc[t] = a2; }
        __syncthreads();
    }
    if (t < NND) atomicMax(&maxD_s, dep[t]);
    if (t < NND) atomicAdd(&lcnt[dep[t]], 1);
    __syncthreads();

    // ---- phase 5: bucket nodes by depth (deterministic, same in all blocks) ----
    if (t < NND){
        int s = 0;
        for (int d2 = 0; d2 < t; ++d2) s += lcnt[d2];
        lstart[t] = s;
    }
    __syncthreads();
    if (t < NND){
        int d2 = dep[t], s = 0;
        for (int c = 0; c < t; ++c) s += (dep[c] == d2);
        order[lstart[d2] + s] = t;
    }
    __syncthreads();

    // ---- main: levels deepest..root; node q of a level -> block (q mod 8) ----
    int w = t >> 6, l = t & 63;
    int c0 = 2*l;                       // gather/stage mapping: 2 cols/lane
    int li = l & 31, hl = l >> 5;       // GEMV mapping: 4 cols x half-d
    int c4 = 4*li, dbase = 64*hl;
    int maxD = maxD_s;

    for (int d = maxD; d >= 0; --d){
        int lo = lstart[d], cnt = lcnt[d];
        for (int q = k + KSP*w; q < cnt; q += KSP*16){
            int n = order[lo + q];                  // wave-uniform
            // gather: base + non-path child contribs (ascending, 4-wide batches)
            float2 bse = *(const float2*)&base[n*DD + c0];
            float e0 = bse.x, e1 = bse.y;
            int cs = cstart[n], cc = ccnt[n];
            for (int j0 = 0; j0 < cc; j0 += 4){
                float2 v0, v1, v2, v3;
                int u0=0, u1=0, u2=0, u3=0;
                if (j0+0 < cc){ int c = cidx[cs+j0+0];
                    if (!(flg_s[c] & SKIPF)){ v0 = *(const float2*)&contribX[((size_t)g*NND+c)*DD + c0]; u0=1; } }
                if (j0+1 < cc){ int c = cidx[cs+j0+1];
                    if (!(flg_s[c] & SKIPF)){ v1 = *(const float2*)&contribX[((size_t)g*NND+c)*DD + c0]; u1=1; } }
                if (j0+2 < cc){ int c = cidx[cs+j0+2];
                    if (!(flg_s[c] & SKIPF)){ v2 = *(const float2*)&contribX[((size_t)g*NND+c)*DD + c0]; u2=1; } }
                if (j0+3 < cc){ int c = cidx[cs+j0+3];
                    if (!(flg_s[c] & SKIPF)){ v3 = *(const float2*)&contribX[((size_t)g*NND+c)*DD + c0]; u3=1; } }
                if (u0){ e0 += v0.x; e1 += v0.y; }   // strictly j-ascending order
                if (u1){ e0 += v1.x; e1 += v1.y; }
                if (u2){ e0 += v2.x; e1 += v2.y; }
                if (u3){ e0 += v3.x; e1 += v3.y; }
            }
            int f = flg_s[n];
            if (f & F_POS){
                if (cc){ e0 = fmaxf(e0, 0.f); e1 = fmaxf(e1, 0.f); }
                *(float2*)&vposG[g*DD + c0] = make_float2(e0, e1);
            } else if (f & F_PATH){
                int slot = ((u32)f) >> 24;
                *(float2*)&uG[((size_t)g*NND + slot)*DD + c0] = make_float2(e0, e1);  // pre-relu
            } else {
                if (cc){ e0 = fmaxf(e0, 0.f); e1 = fmaxf(e1, 0.f); }
                *(float2*)&xstage[w][c0] = make_float2(e0, e1);       // stage emb
                asm volatile("s_waitcnt lgkmcnt(0)" ::: "memory");    // wave-internal RAW
                int e = eid_s[n];
                const float* Wp = EW + (size_t)e*(DD*DD) + (size_t)dbase*DD + c4;
                const float* xr = &xstage[w][dbase];
                float4 A[8], B[8];
                float s0=0.f, s1=0.f, s2=0.f, s3=0.f;
                #define LW(buf, gi) { _Pragma("unroll") \
                    for (int j2 = 0; j2 < 8; ++j2) \
                        buf[j2] = *(const float4*)&Wp[(size_t)((gi)*8 + j2)*DD]; }
                #define CP(buf, gi) { _Pragma("unroll") \
                    for (int j2 = 0; j2 < 8; ++j2){ \
                        float x = xr[(gi)*8 + j2]; \
                        s0 = fmaf(x, buf[j2].x, s0); s1 = fmaf(x, buf[j2].y, s1); \
                        s2 = fmaf(x, buf[j2].z, s2); s3 = fmaf(x, buf[j2].w, s3); } }
                LW(A,0); LW(B,1);
                CP(A,0); LW(A,2);
                CP(B,1); LW(B,3);
                CP(A,2); LW(A,4);
                CP(B,3); LW(B,5);
                CP(A,4); LW(A,6);
                CP(B,5); LW(B,7);
                CP(A,6);
                CP(B,7);
                #undef LW
                #undef CP
                s0 += __shfl_xor(s0, 32); s1 += __shfl_xor(s1, 32);
                s2 += __shfl_xor(s2, 32); s3 += __shfl_xor(s3, 32);
                if (hl == 0){
                    float4 bb = *(const float4*)&EB[(size_t)e*DD + c4];
                    *(float4*)&contribX[((size_t)g*NND + n)*DD + c4] =
                        make_float4(s0 + bb.x, s1 + bb.y, s2 + bb.z, s3 + bb.w);
                }
            }
        }
        __syncthreads();
        if (d > 0){                                  // 8-block level barrier
            if (t == 0){
                __threadfence();                     // release block's contrib stores
                atomicAdd(&flagsG[g*NND + d], 1);
                while (__hip_atomic_load(&flagsG[g*NND + d],
                        __ATOMIC_ACQUIRE, __HIP_MEMORY_SCOPE_AGENT) < KSP)
                    __builtin_amdgcn_s_sleep(1);
                __threadfence();                     // acquire others' stores
            }
            __syncthreads();
        }
    }
}

// ---------------- K3a: step 0, batched over graphs ----------------
__global__ void __launch_bounds__(256, 1) k_step0(
        const float* __restrict__ EW, const float* __restrict__ EB,
        const float* __restrict__ vposG, const float* __restrict__ uG,
        float* __restrict__ V0)
{
    __shared__ __align__(16) float vpos_s[GG][DD];
    int e = blockIdx.x, t = threadIdx.x, l = t & 63, w = t >> 6;
    {
        int idx = t;                                 // GG*DD/4 == 256 exactly
        ((float4*)vpos_s)[idx] = ((const float4*)vposG)[idx];
    }
    __syncthreads();
    int k4 = w*8 + (l & 7);
    int d0 = (l >> 3) * 16;
    bool owner = ((l >> 3) == 0);
    const float* Wp = EW + (size_t)e*(DD*DD) + (size_t)d0*DD + 4*k4;
    float4 wr[16];
    #pragma unroll
    for (int d = 0; d < 16; ++d) wr[d] = *(const float4*)&Wp[d*DD];
    float4 bb = *(const float4*)&EB[(size_t)e*DD + 4*k4];
    for (int g = 0; g < GG; ++g){
        float s0=0.f, s1=0.f, s2=0.f, s3=0.f;
        #pragma unroll
        for (int d = 0; d < 16; ++d){
            float x = vpos_s[g][d0 + d];
            s0 = fmaf(x, wr[d].x, s0);
            s1 = fmaf(x, wr[d].y, s1);
            s2 = fmaf(x, wr[d].z, s2);
            s3 = fmaf(x, wr[d].w, s3);
        }
        #pragma unroll
        for (int m = 8; m <= 32; m <<= 1){
            s0 += __shfl_xor(s0, m); s1 += __shfl_xor(s1, m);
            s2 += __shfl_xor(s2, m); s3 += __shfl_xor(s3, m);
        }
        if (owner){
            float4 u0 = *(const float4*)&uG[(size_t)g*NND*DD + 4*k4];
            float4 r;
            r.x = fmaxf(u0.x + s0 + bb.x, 0.f);
            r.y = fmaxf(u0.y + s1 + bb.y, 0.f);
            r.z = fmaxf(u0.z + s2 + bb.z, 0.f);
            r.w = fmaxf(u0.w + s3 + bb.w, 0.f);
            *(float4*)&V0[((size_t)g*EDGEN + e)*DD + 4*k4] = r;
        }
    }
}

// ---------------- K3b: path chains, 16 e-rows per block ----------------
__global__ void __launch_bounds__(256, 1) k_steps(
        const int* __restrict__ edges,
        const float* __restrict__ EW, const float* __restrict__ EB,
        const float* __restrict__ SEW,
        const float* __restrict__ uG, const float* __restrict__ V0,
        const int* __restrict__ meta, const float* __restrict__ dscore,
        float* __restrict__ outp)
{
    __shared__ __align__(16) float Vbuf[2][CH2][DD];
    __shared__ float red[CH2][4];
    int g = blockIdx.x >> 3, chunk = blockIdx.x & 7;
    int t = threadIdx.x, l = t & 63, w = t >> 6;
    int k4 = w*8 + (l & 7);
    int d0 = (l >> 3) * 16;
    bool owner = ((l >> 3) == 0);
    int eBase = chunk * CH2;
    int L = meta[g*(NND+1)];

    // load this block's 16 step-0 rows
    for (int idx = t; idx < CH2*DD/4; idx += 256)
        ((float4*)&Vbuf[0][0][0])[idx] =
            ((const float4*)&V0[((size_t)g*EDGEN + eBase)*DD])[idx];
    __syncthreads();

    // ---- shared steps 1..L-1: one W per step, reused across CH2 e-rows ----
    int cur = 0;
    for (int s = 1; s < L; ++s){
        int pn = meta[g*(NND+1) + s];           // path[s-1]
        int ej = edges[pn];
        const float* Wp = EW + (size_t)ej*(DD*DD) + (size_t)d0*DD + 4*k4;
        float4 wr[16];
        #pragma unroll
        for (int d = 0; d < 16; ++d) wr[d] = *(const float4*)&Wp[d*DD];
        float4 us = *(const float4*)&uG[((size_t)g*NND + s)*DD + 4*k4];
        float4 bb = *(const float4*)&EB[(size_t)ej*DD + 4*k4];
        #pragma unroll 4
        for (int p = 0; p < CH2; ++p){
            float ev[16];
            #pragma unroll
            for (int j = 0; j < 4; ++j){
                float4 x = *(const float4*)&Vbuf[cur][p][d0 + 4*j];
                ev[4*j+0]=x.x; ev[4*j+1]=x.y; ev[4*j+2]=x.z; ev[4*j+3]=x.w;
            }
            float s0=0.f, s1=0.f, s2=0.f, s3=0.f;
            #pragma unroll
            for (int d = 0; d < 16; ++d){
                s0 = fmaf(ev[d], wr[d].x, s0);
                s1 = fmaf(ev[d], wr[d].y, s1);
                s2 = fmaf(ev[d], wr[d].z, s2);
                s3 = fmaf(ev[d], wr[d].w, s3);
            }
            #pragma unroll
            for (int m = 8; m <= 32; m <<= 1){
                s0 += __shfl_xor(s0, m); s1 += __shfl_xor(s1, m);
                s2 += __shfl_xor(s2, m); s3 += __shfl_xor(s3, m);
            }
            if (owner){
                float4 r;
                r.x = fmaxf(us.x + s0 + bb.x, 0.f);
                r.y = fmaxf(us.y + s1 + bb.y, 0.f);
                r.z = fmaxf(us.z + s2 + bb.z, 0.f);
                r.w = fmaxf(us.w + s3 + bb.w, 0.f);
                *(float4*)&Vbuf[cur^1][p][4*k4] = r;
            }
        }
        __syncthreads();
        cur ^= 1;
    }

    // ---- final transform (root edge) + score ----
    {
        int rn = meta[g*(NND+1) + L];           // path[L-1] (= 127)
        int er = edges[rn];
        const float* Wp = EW + (size_t)er*(DD*DD) + (size_t)d0*DD + 4*k4;
        float4 wr[16];
        #pragma unroll
        for (int d = 0; d < 16; ++d) wr[d] = *(const float4*)&Wp[d*DD];
        float4 bb = *(const float4*)&EB[(size_t)er*DD + 4*k4];
        float4 sw = *(const float4*)&SEW[4*k4];
        #pragma unroll 4
        for (int p = 0; p < CH2; ++p){
            float ev[16];
            #pragma unroll
            for (int j = 0; j < 4; ++j){
                float4 x = *(const float4*)&Vbuf[cur][p][d0 + 4*j];
                ev[4*j+0]=x.x; ev[4*j+1]=x.y; ev[4*j+2]=x.z; ev[4*j+3]=x.w;
            }
            float s0=0.f, s1=0.f, s2=0.f, s3=0.f;
            #pragma unroll
            for (int d = 0; d < 16; ++d){
                s0 = fmaf(ev[d], wr[d].x, s0);
                s1 = fmaf(ev[d], wr[d].y, s1);
                s2 = fmaf(ev[d], wr[d].z, s2);
                s3 = fmaf(ev[d], wr[d].w, s3);
            }
            #pragma unroll
            for (int m = 8; m <= 32; m <<= 1){
                s0 += __shfl_xor(s0, m); s1 += __shfl_xor(s1, m);
                s2 += __shfl_xor(s2, m); s3 += __shfl_xor(s3, m);
            }
            if (owner){
                float part = (s0 + bb.x) * sw.x + (s1 + bb.y) * sw.y
                           + (s2 + bb.z) * sw.z + (s3 + bb.w) * sw.w;
                part += __shfl_xor(part, 1);
                part += __shfl_xor(part, 2);
                part += __shfl_xor(part, 4);
                if (l == 0) red[p][w] = part;
            }
        }
        __syncthreads();
        if (t < CH2)
            outp[g*DD + eBase + t] = dscore[0] + red[t][0] + red[t][1] + red[t][2] + red[t][3];
    }
}

extern "C" void kernel_launch(void* const* d_in, const int* in_sizes, int n_in,
                              void* d_out, int out_size, void* d_ws, size_t ws_size,
                              hipStream_t stream)
{
    const int*   data   = (const int*)d_in[0];
    /* d_in[1] = types, unused (single data_type) */
    const int*   graphs = (const int*)d_in[2];
    const int*   edges  = (const int*)d_in[3];
    const int*   posArr = (const int*)d_in[4];
    const float* vecs   = (const float*)d_in[5];
    const float* dw     = (const float*)d_in[6];
    const float* db     = (const float*)d_in[7];
    const float* ew     = (const float*)d_in[8];
    const float* eb     = (const float*)d_in[9];
    const float* sew    = (const float*)d_in[10];
    const float* sdw    = (const float*)d_in[11];
    const float* sb     = (const float*)d_in[12];

    char* ws = (char*)d_ws;
    float* base   = (float*)(ws);                               // 64 KB
    float* vposG  = (float*)(ws + 65536);                       // 4 KB
    float* uG     = (float*)(ws + 69632);                       // 512 KB
    float* dscore = (float*)(ws + 593920);                      // 1 f32
    int*   meta   = (int*)  (ws + 594176);                      // 8*129 ints
    float* V0     = (float*)(ws + 598528);                      // 512 KB (k_step0->k_steps)
    float* contribX = V0;                                       // overlay: dead before k_step0
    int*   flagsG = (int*)  (ws + 1122816);                     // 8*128 ints

    float* outp = (float*)d_out;

    k_base <<<NND, 128, 0, stream>>>(data, posArr, vecs, dw, db, sdw, sb,
                                     base, dscore, flagsG);
    k_treeX<<<GG*KSP, 1024, 0, stream>>>(graphs, edges, posArr, ew, eb, base,
                                         vposG, uG, meta, contribX, flagsG);
    k_step0<<<EDGEN, 256, 0, stream>>>(ew, eb, vposG, uG, V0);
    k_steps<<<GG*(EDGEN/CH2), 256, 0, stream>>>(edges, ew, eb, sew, uG, V0,
                                                meta, dscore, outp);
}